// Round 1
// baseline (2375.394 us; speedup 1.0000x reference)
//
#include <hip/hip_runtime.h>
#include <math.h>

static constexpr int K = 512;
static constexpr int D = 256;
static constexpr int NB = 64;
static constexpr int NP = K / NB;            // 8 panels
static constexpr float ALPHA = 0.99f;
static constexpr float EPSF  = 2.2204460492503131e-16f;

// ============================ anchors =====================================
__global__ __launch_bounds__(256) void anchors_kernel(
    const float* __restrict__ F, const float* __restrict__ Q, int* __restrict__ anchors)
{
  const int b = blockIdx.x;
  const float* Fb = F + (size_t)b * (K * D);
  __shared__ __align__(16) float qs[D];
  __shared__ float sim[K];
  __shared__ float rv[256];
  __shared__ int   ri[256];
  const int t = threadIdx.x;
  const int wave = t >> 6, lane = t & 63;

  qs[t] = Q[(size_t)b * D + t];
  __syncthreads();

  // round 1: sim[k] = q . f_k  (wave-per-k, lane-parallel over D)
  for (int k = wave; k < K; k += 4) {
    const float4 f4 = *(const float4*)(Fb + (size_t)k * D + lane * 4);
    const float4 q4 = *(const float4*)(qs + lane * 4);
    float p = f4.x*q4.x + f4.y*q4.y + f4.z*q4.z + f4.w*q4.w;
    #pragma unroll
    for (int off = 32; off >= 1; off >>= 1) p += __shfl_down(p, off, 64);
    if (lane == 0) sim[k] = p;
  }
  __syncthreads();

  // argmin #1 (first-occurrence tie-break)
  {
    float v0 = sim[t]; int i0 = t;
    float v1 = sim[t + 256];
    if (v1 < v0) { v0 = v1; i0 = t + 256; }
    rv[t] = v0; ri[t] = i0;
  }
  __syncthreads();
  for (int s = 128; s > 0; s >>= 1) {
    if (t < s) {
      float ov = rv[t + s]; int oi = ri[t + s];
      if (ov < rv[t] || (ov == rv[t] && oi < ri[t])) { rv[t] = ov; ri[t] = oi; }
    }
    __syncthreads();
  }
  const int a0 = ri[0];
  __syncthreads();

  // round 2: sim[k] = max(sim[k], f_a0 . f_k)
  qs[t] = Fb[(size_t)a0 * D + t];
  __syncthreads();
  for (int k = wave; k < K; k += 4) {
    const float4 f4 = *(const float4*)(Fb + (size_t)k * D + lane * 4);
    const float4 q4 = *(const float4*)(qs + lane * 4);
    float p = f4.x*q4.x + f4.y*q4.y + f4.z*q4.z + f4.w*q4.w;
    #pragma unroll
    for (int off = 32; off >= 1; off >>= 1) p += __shfl_down(p, off, 64);
    if (lane == 0) sim[k] = fmaxf(sim[k], p);
  }
  __syncthreads();

  // argmin #2
  {
    float v0 = sim[t]; int i0 = t;
    float v1 = sim[t + 256];
    if (v1 < v0) { v0 = v1; i0 = t + 256; }
    rv[t] = v0; ri[t] = i0;
  }
  __syncthreads();
  for (int s = 128; s > 0; s >>= 1) {
    if (t < s) {
      float ov = rv[t + s]; int oi = ri[t + s];
      if (ov < rv[t] || (ov == rv[t] && oi < ri[t])) { rv[t] = ov; ri[t] = oi; }
    }
    __syncthreads();
  }
  const int a1 = ri[0];
  if (t == 0) { anchors[2 * b] = a0; anchors[2 * b + 1] = a1; }
}

// ============================ gram: W = exp(F F^T), zero diag =============
__global__ __launch_bounds__(256) void gram_kernel(
    const float* __restrict__ F, float* __restrict__ W)
{
  const int b  = blockIdx.z;
  const int r0 = blockIdx.y * 64;
  const int c0 = blockIdx.x * 64;
  const float* Fb = F + (size_t)b * (K * D);
  float* Wb = W + (size_t)b * (K * K);

  __shared__ __align__(16) float As[64][68];   // [d][row], padded (272B rows)
  __shared__ __align__(16) float Bs[64][68];   // [d][col]
  const int t = threadIdx.x;
  const int tx = t & 15, ty = t >> 4;

  float acc[4][4] = {{0.f}};

  for (int kk = 0; kk < D; kk += 64) {
    __syncthreads();
    {
      const int row = t >> 2;
      const int dp  = (t & 3) * 16;
      const float* srcA = Fb + (size_t)(r0 + row) * D + kk + dp;
      const float* srcB = Fb + (size_t)(c0 + row) * D + kk + dp;
      #pragma unroll
      for (int q = 0; q < 4; ++q) {
        float4 v = *(const float4*)(srcA + q * 4);
        As[dp + q*4 + 0][row] = v.x; As[dp + q*4 + 1][row] = v.y;
        As[dp + q*4 + 2][row] = v.z; As[dp + q*4 + 3][row] = v.w;
      }
      #pragma unroll
      for (int q = 0; q < 4; ++q) {
        float4 v = *(const float4*)(srcB + q * 4);
        Bs[dp + q*4 + 0][row] = v.x; Bs[dp + q*4 + 1][row] = v.y;
        Bs[dp + q*4 + 2][row] = v.z; Bs[dp + q*4 + 3][row] = v.w;
      }
    }
    __syncthreads();
    #pragma unroll 4
    for (int k = 0; k < 64; ++k) {
      const float4 a4 = *(const float4*)&As[k][ty * 4];
      const float4 b4 = *(const float4*)&Bs[k][tx * 4];
      const float a[4] = {a4.x, a4.y, a4.z, a4.w};
      const float bb[4] = {b4.x, b4.y, b4.z, b4.w};
      #pragma unroll
      for (int i = 0; i < 4; ++i)
        #pragma unroll
        for (int j = 0; j < 4; ++j) acc[i][j] += a[i] * bb[j];
    }
  }

  const int gc0 = c0 + tx * 4;
  #pragma unroll
  for (int i = 0; i < 4; ++i) {
    const int gr = r0 + ty * 4 + i;
    float4 o;
    o.x = (gr == gc0 + 0) ? 0.f : expf(acc[i][0]);
    o.y = (gr == gc0 + 1) ? 0.f : expf(acc[i][1]);
    o.z = (gr == gc0 + 2) ? 0.f : expf(acc[i][2]);
    o.w = (gr == gc0 + 3) ? 0.f : expf(acc[i][3]);
    *(float4*)(Wb + (size_t)gr * K + gc0) = o;
  }
}

// ============================ dinv = 1/sqrt(colsum(W)+eps) ================
__global__ __launch_bounds__(256) void dinv_kernel(
    const float* __restrict__ W, float* __restrict__ dinv)
{
  const int idx = blockIdx.x * 256 + threadIdx.x;  // B*K total
  const int b = idx >> 9, m = idx & (K - 1);
  const float* Wb = W + (size_t)b * (K * K);
  float s = 0.f;
  for (int k = 0; k < K; ++k) s += Wb[(size_t)k * K + m];
  dinv[idx] = 1.0f / sqrtf(s + EPSF);
}

// ============================ A = I - alpha * d W d + eps =================
__global__ __launch_bounds__(256) void normalize_kernel(
    float* __restrict__ A, const float* __restrict__ dinv)
{
  const size_t e4 = (size_t)blockIdx.x * 256 + threadIdx.x;  // float4 index
  const int b   = (int)(e4 >> 16);          // K*K/4 = 65536
  const int rem = (int)(e4 & 65535);
  const int i   = rem >> 7;                 // K/4 = 128 float4 per row
  const int j   = (rem & 127) * 4;
  float4 w = ((const float4*)A)[e4];
  const float  di = dinv[b * K + i];
  const float4 dj = *(const float4*)(dinv + b * K + j);
  float4 o;
  o.x = ((i == j + 0) ? 1.f : 0.f) - ALPHA * di * w.x * dj.x + EPSF;
  o.y = ((i == j + 1) ? 1.f : 0.f) - ALPHA * di * w.y * dj.y + EPSF;
  o.z = ((i == j + 2) ? 1.f : 0.f) - ALPHA * di * w.z * dj.z + EPSF;
  o.w = ((i == j + 3) ? 1.f : 0.f) - ALPHA * di * w.w * dj.w + EPSF;
  ((float4*)A)[e4] = o;
}

// ==== diag block Cholesky + explicit triangular inverse V = L11^{-1} ======
__global__ __launch_bounds__(256) void diag_kernel(
    float* __restrict__ A, float* __restrict__ Vbuf, int pj)
{
  const int b = blockIdx.x;
  float* Ab = A + (size_t)b * (K * K);
  float* Vb = Vbuf + (size_t)b * (NB * NB);
  const int j0 = pj * NB;
  __shared__ float Ld[NB * 65];
  __shared__ float Vs[NB * 65];
  __shared__ float ds[NB];
  const int t = threadIdx.x;

  for (int idx = t; idx < NB * NB; idx += 256) {
    const int r = idx >> 6, c = idx & 63;
    Ld[r * 65 + c] = Ab[(size_t)(j0 + r) * K + j0 + c];
  }
  __syncthreads();

  // right-looking Cholesky on full symmetric 64x64 block (rows+cols scaled)
  for (int k = 0; k < NB; ++k) {
    const float v = Ld[k * 65 + k];
    const float d = sqrtf(v);
    const float inv = 1.0f / d;
    if (t == 0) ds[k] = d;
    if (t < 64) { if (t > k) Ld[t * 65 + k] *= inv; }
    else if (t < 128) { const int c = t - 64; if (c > k) Ld[k * 65 + c] *= inv; }
    __syncthreads();
    for (int idx = t; idx < NB * NB; idx += 256) {
      const int i = idx >> 6, c = idx & 63;
      if (i > k && c > k) Ld[i * 65 + c] -= Ld[i * 65 + k] * Ld[k * 65 + c];
    }
    __syncthreads();
  }

  // V = L11^{-1}: sequential over rows, parallel over columns
  for (int r = 0; r < NB; ++r) {
    if (t < 64) {
      const int c = t;
      float acc = (r == c) ? 1.0f : 0.0f;
      for (int i = c; i < r; ++i) acc -= Ld[r * 65 + i] * Vs[i * 65 + c];
      Vs[r * 65 + c] = (c <= r) ? (acc / ds[r]) : 0.0f;
    }
    __syncthreads();
  }

  // write back: L11 lower + diag, L11^T upper (Ld upper == exact transpose)
  for (int idx = t; idx < NB * NB; idx += 256) {
    const int r = idx >> 6, c = idx & 63;
    Ab[(size_t)(j0 + r) * K + j0 + c] = (r == c) ? ds[r] : Ld[r * 65 + c];
    Vb[idx] = Vs[r * 65 + c];
  }
}

// ============ L21 = A21 * V^T  (+ mirror L21^T into upper band) ===========
__global__ __launch_bounds__(256) void l21_kernel(
    float* __restrict__ A, const float* __restrict__ Vbuf, int pj)
{
  const int b = blockIdx.y;
  const int j0 = pj * NB;
  const int r0 = j0 + NB + blockIdx.x * 64;
  float* Ab = A + (size_t)b * (K * K);
  const float* Vb = Vbuf + (size_t)b * (NB * NB);
  __shared__ __align__(16) float As[64][68];   // [i][row] = A21[row][i]
  __shared__ __align__(16) float Bs[64][68];   // [i][col] = V[col][i]
  const int t = threadIdx.x;
  const int tx = t & 15, ty = t >> 4;

  for (int idx = t; idx < 4096; idx += 256) {
    const int r = idx >> 6, c = idx & 63;
    As[c][r] = Ab[(size_t)(r0 + r) * K + j0 + c];
    Bs[c][r] = Vb[r * 64 + c];
  }
  __syncthreads();

  float acc[4][4] = {{0.f}};
  #pragma unroll 4
  for (int k = 0; k < 64; ++k) {
    const float4 a4 = *(const float4*)&As[k][ty * 4];
    const float4 b4 = *(const float4*)&Bs[k][tx * 4];
    const float a[4] = {a4.x, a4.y, a4.z, a4.w};
    const float bb[4] = {b4.x, b4.y, b4.z, b4.w};
    #pragma unroll
    for (int i = 0; i < 4; ++i)
      #pragma unroll
      for (int j = 0; j < 4; ++j) acc[i][j] += a[i] * bb[j];
  }

  // normal write (coalesced)
  #pragma unroll
  for (int i = 0; i < 4; ++i) {
    float4 o; o.x = acc[i][0]; o.y = acc[i][1]; o.z = acc[i][2]; o.w = acc[i][3];
    *(float4*)(Ab + (size_t)(r0 + ty * 4 + i) * K + j0 + tx * 4) = o;
  }
  __syncthreads();
  // stage transpose in LDS then coalesced mirror write to upper band
  #pragma unroll
  for (int i = 0; i < 4; ++i)
    #pragma unroll
    for (int j = 0; j < 4; ++j) As[tx * 4 + j][ty * 4 + i] = acc[i][j];
  __syncthreads();
  for (int idx = t; idx < 4096; idx += 256) {
    const int cc = idx >> 6, rr = idx & 63;
    Ab[(size_t)(j0 + cc) * K + r0 + rr] = As[cc][rr];
  }
}

// ============ trailing: A22 -= L21 L21^T (lower tiles only) ===============
__global__ __launch_bounds__(256) void trailing_kernel(float* __restrict__ A, int pj)
{
  const int b = blockIdx.y;
  const int j0 = pj * NB;
  const int j1 = j0 + NB;
  const int tl = blockIdx.x;
  int bi = 0; while ((bi + 1) * (bi + 2) / 2 <= tl) ++bi;
  const int bj = tl - bi * (bi + 1) / 2;
  const int r0 = j1 + bi * 64, c0 = j1 + bj * 64;
  float* Ab = A + (size_t)b * (K * K);
  __shared__ __align__(16) float As[64][68];
  __shared__ __align__(16) float Bs[64][68];
  const int t = threadIdx.x;
  const int tx = t & 15, ty = t >> 4;

  for (int idx = t; idx < 4096; idx += 256) {
    const int r = idx >> 6, c = idx & 63;
    As[c][r] = Ab[(size_t)(r0 + r) * K + j0 + c];
    Bs[c][r] = Ab[(size_t)(c0 + r) * K + j0 + c];
  }
  __syncthreads();

  float acc[4][4] = {{0.f}};
  #pragma unroll 4
  for (int k = 0; k < 64; ++k) {
    const float4 a4 = *(const float4*)&As[k][ty * 4];
    const float4 b4 = *(const float4*)&Bs[k][tx * 4];
    const float a[4] = {a4.x, a4.y, a4.z, a4.w};
    const float bb[4] = {b4.x, b4.y, b4.z, b4.w};
    #pragma unroll
    for (int i = 0; i < 4; ++i)
      #pragma unroll
      for (int j = 0; j < 4; ++j) acc[i][j] += a[i] * bb[j];
  }

  #pragma unroll
  for (int i = 0; i < 4; ++i) {
    float* p = Ab + (size_t)(r0 + ty * 4 + i) * K + c0 + tx * 4;
    float4 v = *(const float4*)p;
    v.x -= acc[i][0]; v.y -= acc[i][1]; v.z -= acc[i][2]; v.w -= acc[i][3];
    *(float4*)p = v;
  }
}

// ============ blocked triangular solves, both RHS in LDS ==================
__global__ __launch_bounds__(256) void solve_kernel(
    const float* __restrict__ A, const int* __restrict__ anchors, float* __restrict__ out)
{
  const int b = blockIdx.x;
  const float* Ab = A + (size_t)b * (K * K);
  __shared__ __align__(16) float xs0[K], xs1[K];
  __shared__ float Ld[64 * 65];
  const int t = threadIdx.x;
  const int a0 = anchors[2 * b], a1 = anchors[2 * b + 1];

  for (int k = t; k < K; k += 256) {
    xs0[k] = (k == a0) ? 1.f : 0.f;
    xs1[k] = (k == a1) ? 1.f : 0.f;
  }
  __syncthreads();

  // ---- forward: L x = y
  for (int blk = 0; blk < NP; ++blk) {
    const int R0 = blk * 64;
    if (blk > 0) {
      const int g = t >> 2, tg = t & 3;
      const int r = R0 + g;
      const float* rowp = Ab + (size_t)r * K;
      float s0 = 0.f, s1 = 0.f;
      for (int j = tg * 4; j < R0; j += 16) {
        const float4 l4 = *(const float4*)(rowp + j);
        const float4 p0 = *(const float4*)(xs0 + j);
        const float4 p1 = *(const float4*)(xs1 + j);
        s0 += l4.x*p0.x + l4.y*p0.y + l4.z*p0.z + l4.w*p0.w;
        s1 += l4.x*p1.x + l4.y*p1.y + l4.z*p1.z + l4.w*p1.w;
      }
      s0 += __shfl_down(s0, 2, 64); s0 += __shfl_down(s0, 1, 64);
      s1 += __shfl_down(s1, 2, 64); s1 += __shfl_down(s1, 1, 64);
      if (tg == 0) { xs0[r] -= s0; xs1[r] -= s1; }
    }
    for (int idx = t; idx < 4096; idx += 256) {
      const int rr = idx >> 6, cc = idx & 63;
      Ld[rr * 65 + cc] = Ab[(size_t)(R0 + rr) * K + R0 + cc];
    }
    __syncthreads();
    if (t < 64) {
      const int l = t;
      float xr0 = xs0[R0 + l], xr1 = xs1[R0 + l];
      const float invd = 1.0f / Ld[l * 65 + l];
      for (int j = 0; j < 64; ++j) {
        const float bj0 = __shfl(xr0, j, 64);
        const float bj1 = __shfl(xr1, j, 64);
        const float idj = __shfl(invd, j, 64);
        const float xj0 = bj0 * idj, xj1 = bj1 * idj;
        if (l == j) { xr0 = xj0; xr1 = xj1; }
        else if (l > j) { const float lij = Ld[l * 65 + j]; xr0 -= lij * xj0; xr1 -= lij * xj1; }
      }
      xs0[R0 + l] = xr0; xs1[R0 + l] = xr1;
    }
    __syncthreads();
  }

  // ---- backward: L^T x = z (upper triangle holds L^T)
  for (int blk = NP - 1; blk >= 0; --blk) {
    const int R0 = blk * 64;
    if (blk < NP - 1) {
      const int g = t >> 2, tg = t & 3;
      const int r = R0 + g;
      const float* rowp = Ab + (size_t)r * K;
      float s0 = 0.f, s1 = 0.f;
      for (int j = R0 + 64 + tg * 4; j < K; j += 16) {
        const float4 l4 = *(const float4*)(rowp + j);
        const float4 p0 = *(const float4*)(xs0 + j);
        const float4 p1 = *(const float4*)(xs1 + j);
        s0 += l4.x*p0.x + l4.y*p0.y + l4.z*p0.z + l4.w*p0.w;
        s1 += l4.x*p1.x + l4.y*p1.y + l4.z*p1.z + l4.w*p1.w;
      }
      s0 += __shfl_down(s0, 2, 64); s0 += __shfl_down(s0, 1, 64);
      s1 += __shfl_down(s1, 2, 64); s1 += __shfl_down(s1, 1, 64);
      if (tg == 0) { xs0[r] -= s0; xs1[r] -= s1; }
    }
    for (int idx = t; idx < 4096; idx += 256) {
      const int rr = idx >> 6, cc = idx & 63;
      Ld[rr * 65 + cc] = Ab[(size_t)(R0 + rr) * K + R0 + cc];
    }
    __syncthreads();
    if (t < 64) {
      const int l = t;
      float xr0 = xs0[R0 + l], xr1 = xs1[R0 + l];
      const float invd = 1.0f / Ld[l * 65 + l];
      for (int j = 63; j >= 0; --j) {
        const float bj0 = __shfl(xr0, j, 64);
        const float bj1 = __shfl(xr1, j, 64);
        const float idj = __shfl(invd, j, 64);
        const float xj0 = bj0 * idj, xj1 = bj1 * idj;
        if (l == j) { xr0 = xj0; xr1 = xj1; }
        else if (l < j) { const float u = Ld[l * 65 + j]; xr0 -= u * xj0; xr1 -= u * xj1; }
      }
      xs0[R0 + l] = xr0; xs1[R0 + l] = xr1;
    }
    __syncthreads();
  }

  for (int k = t; k < K; k += 256) {
    out[((size_t)b * K + k) * 2 + 0] = xs0[k];
    out[((size_t)b * K + k) * 2 + 1] = xs1[k];
  }
}

// ==========================================================================
extern "C" void kernel_launch(void* const* d_in, const int* in_sizes, int n_in,
                              void* d_out, int out_size, void* d_ws, size_t ws_size,
                              hipStream_t stream) {
  const float* F = (const float*)d_in[0];   // [B,K,D]
  const float* Q = (const float*)d_in[1];   // [B,D]
  float* out = (float*)d_out;               // [B,K,2]
  const int B = in_sizes[1] / D;            // 128

  float* Abuf  = (float*)d_ws;                         // B*K*K
  float* dinvp = Abuf + (size_t)B * K * K;             // B*K
  float* Vbuf  = dinvp + (size_t)B * K;                // B*64*64
  int*   anch  = (int*)(Vbuf + (size_t)B * NB * NB);   // B*2

  anchors_kernel<<<B, 256, 0, stream>>>(F, Q, anch);
  gram_kernel<<<dim3(K / 64, K / 64, B), 256, 0, stream>>>(F, Abuf);
  dinv_kernel<<<(B * K) / 256, 256, 0, stream>>>(Abuf, dinvp);
  normalize_kernel<<<(int)(((size_t)B * K * K / 4) / 256), 256, 0, stream>>>(Abuf, dinvp);

  for (int pj = 0; pj < NP; ++pj) {
    diag_kernel<<<B, 256, 0, stream>>>(Abuf, Vbuf, pj);
    const int T = NP - pj - 1;
    if (T > 0) {
      l21_kernel<<<dim3(T, B), 256, 0, stream>>>(Abuf, Vbuf, pj);
      trailing_kernel<<<dim3(T * (T + 1) / 2, B), 256, 0, stream>>>(Abuf, pj);
    }
  }

  solve_kernel<<<B, 256, 0, stream>>>(Abuf, anch, out);
}

// Round 2
// 2249.067 us; speedup vs baseline: 1.0562x; 1.0562x over previous
//
#include <hip/hip_runtime.h>
#include <math.h>

static constexpr int K = 512;
static constexpr int D = 256;
static constexpr int NB = 64;
static constexpr int NP = K / NB;            // 8 panels
static constexpr float ALPHA = 0.99f;
static constexpr float EPSF  = 2.2204460492503131e-16f;

// ============================ anchors =====================================
__global__ __launch_bounds__(256) void anchors_kernel(
    const float* __restrict__ F, const float* __restrict__ Q, int* __restrict__ anchors)
{
  const int b = blockIdx.x;
  const float* Fb = F + (size_t)b * (K * D);
  __shared__ __align__(16) float qs[D];
  __shared__ float sim[K];
  __shared__ float rv[256];
  __shared__ int   ri[256];
  const int t = threadIdx.x;
  const int wave = t >> 6, lane = t & 63;

  qs[t] = Q[(size_t)b * D + t];
  __syncthreads();

  for (int k = wave; k < K; k += 4) {
    const float4 f4 = *(const float4*)(Fb + (size_t)k * D + lane * 4);
    const float4 q4 = *(const float4*)(qs + lane * 4);
    float p = f4.x*q4.x + f4.y*q4.y + f4.z*q4.z + f4.w*q4.w;
    #pragma unroll
    for (int off = 32; off >= 1; off >>= 1) p += __shfl_down(p, off, 64);
    if (lane == 0) sim[k] = p;
  }
  __syncthreads();

  {
    float v0 = sim[t]; int i0 = t;
    float v1 = sim[t + 256];
    if (v1 < v0) { v0 = v1; i0 = t + 256; }
    rv[t] = v0; ri[t] = i0;
  }
  __syncthreads();
  for (int s = 128; s > 0; s >>= 1) {
    if (t < s) {
      float ov = rv[t + s]; int oi = ri[t + s];
      if (ov < rv[t] || (ov == rv[t] && oi < ri[t])) { rv[t] = ov; ri[t] = oi; }
    }
    __syncthreads();
  }
  const int a0 = ri[0];
  __syncthreads();

  qs[t] = Fb[(size_t)a0 * D + t];
  __syncthreads();
  for (int k = wave; k < K; k += 4) {
    const float4 f4 = *(const float4*)(Fb + (size_t)k * D + lane * 4);
    const float4 q4 = *(const float4*)(qs + lane * 4);
    float p = f4.x*q4.x + f4.y*q4.y + f4.z*q4.z + f4.w*q4.w;
    #pragma unroll
    for (int off = 32; off >= 1; off >>= 1) p += __shfl_down(p, off, 64);
    if (lane == 0) sim[k] = fmaxf(sim[k], p);
  }
  __syncthreads();

  {
    float v0 = sim[t]; int i0 = t;
    float v1 = sim[t + 256];
    if (v1 < v0) { v0 = v1; i0 = t + 256; }
    rv[t] = v0; ri[t] = i0;
  }
  __syncthreads();
  for (int s = 128; s > 0; s >>= 1) {
    if (t < s) {
      float ov = rv[t + s]; int oi = ri[t + s];
      if (ov < rv[t] || (ov == rv[t] && oi < ri[t])) { rv[t] = ov; ri[t] = oi; }
    }
    __syncthreads();
  }
  const int a1 = ri[0];
  if (t == 0) { anchors[2 * b] = a0; anchors[2 * b + 1] = a1; }
}

// ===== gram (lower triangle only): W = exp(F F^T), zero diag, + degree ====
__global__ __launch_bounds__(256) void gram_kernel(
    const float* __restrict__ F, float* __restrict__ W, float* __restrict__ Dg)
{
  const int b  = blockIdx.z;
  const int ti = blockIdx.x;                   // 0..35 lower-tri tile id
  int bi = 0; while ((bi + 1) * (bi + 2) / 2 <= ti) ++bi;
  const int bj = ti - bi * (bi + 1) / 2;
  const int r0 = bi * 64, c0 = bj * 64;
  const float* Fb = F + (size_t)b * (K * D);
  float* Wb = W + (size_t)b * (K * K);

  __shared__ __align__(16) float As[64][68];   // [d][row]
  __shared__ __align__(16) float Bs[64][68];   // [d][col]
  __shared__ float csum[16][68];
  const int t = threadIdx.x;
  const int tx = t & 15, ty = t >> 4;
  const int row = t >> 2, g = t & 3;           // loader mapping (conflict-free)

  float acc[4][4] = {{0.f}};
  float (*Bsel)[68] = (bi == bj) ? As : Bs;

  for (int kk = 0; kk < D; kk += 64) {
    __syncthreads();
    {
      const float* srcA = Fb + (size_t)(r0 + row) * D + kk + g * 4;
      #pragma unroll
      for (int q = 0; q < 4; ++q) {
        const float4 v = *(const float4*)(srcA + q * 16);
        const int d = g * 4 + q * 16;
        As[d+0][row] = v.x; As[d+1][row] = v.y; As[d+2][row] = v.z; As[d+3][row] = v.w;
      }
      if (bi != bj) {
        const float* srcB = Fb + (size_t)(c0 + row) * D + kk + g * 4;
        #pragma unroll
        for (int q = 0; q < 4; ++q) {
          const float4 v = *(const float4*)(srcB + q * 16);
          const int d = g * 4 + q * 16;
          Bs[d+0][row] = v.x; Bs[d+1][row] = v.y; Bs[d+2][row] = v.z; Bs[d+3][row] = v.w;
        }
      }
    }
    __syncthreads();
    #pragma unroll 4
    for (int k = 0; k < 64; ++k) {
      const float4 a4 = *(const float4*)&As[k][ty * 4];
      const float4 b4 = *(const float4*)&Bsel[k][tx * 4];
      const float a[4] = {a4.x, a4.y, a4.z, a4.w};
      const float bb[4] = {b4.x, b4.y, b4.z, b4.w};
      #pragma unroll
      for (int i = 0; i < 4; ++i)
        #pragma unroll
        for (int j = 0; j < 4; ++j) acc[i][j] += a[i] * bb[j];
    }
  }

  // epilogue: exp, zero diag, store, degree sums
  const int gc0 = c0 + tx * 4;
  float colp[4] = {0.f, 0.f, 0.f, 0.f};
  float rowp_[4];
  #pragma unroll
  for (int i = 0; i < 4; ++i) {
    const int gr = r0 + ty * 4 + i;
    float4 o;
    o.x = (gr == gc0 + 0) ? 0.f : expf(acc[i][0]);
    o.y = (gr == gc0 + 1) ? 0.f : expf(acc[i][1]);
    o.z = (gr == gc0 + 2) ? 0.f : expf(acc[i][2]);
    o.w = (gr == gc0 + 3) ? 0.f : expf(acc[i][3]);
    *(float4*)(Wb + (size_t)gr * K + gc0) = o;
    rowp_[i] = o.x + o.y + o.z + o.w;
    colp[0] += o.x; colp[1] += o.y; colp[2] += o.z; colp[3] += o.w;
  }
  #pragma unroll
  for (int i = 0; i < 4; ++i) {
    float v = rowp_[i];
    v += __shfl_down(v, 8, 16); v += __shfl_down(v, 4, 16);
    v += __shfl_down(v, 2, 16); v += __shfl_down(v, 1, 16);
    if (tx == 0) atomicAdd(&Dg[(size_t)b * K + r0 + ty * 4 + i], v);
  }
  if (bi != bj) {   // symmetric contribution to columns' degrees
    csum[ty][tx * 4 + 0] = colp[0]; csum[ty][tx * 4 + 1] = colp[1];
    csum[ty][tx * 4 + 2] = colp[2]; csum[ty][tx * 4 + 3] = colp[3];
    __syncthreads();
    if (t < 64) {
      float s = 0.f;
      #pragma unroll
      for (int y = 0; y < 16; ++y) s += csum[y][t];
      atomicAdd(&Dg[(size_t)b * K + c0 + t], s);
    }
  }
}

// ================= fused Cholesky + triangular solves =====================
__device__ __forceinline__ void stage_tile(float (*dst)[68], const float* __restrict__ Ab,
                                           int row0, int col0, int t) {
  const int row = t >> 2, g = t & 3;
  const float* src = Ab + (size_t)(row0 + row) * K + col0 + g * 4;
  #pragma unroll
  for (int q = 0; q < 4; ++q) {
    const float4 v = *(const float4*)(src + q * 16);
    const int d = g * 4 + q * 16;
    dst[d+0][row] = v.x; dst[d+1][row] = v.y; dst[d+2][row] = v.z; dst[d+3][row] = v.w;
  }
}

__device__ __forceinline__ void init_acc(float acc[4][4], const float* __restrict__ Ab,
                                         const float* dinv_s, int r0, int c0,
                                         int tx, int ty) {
  const int cbase = c0 + tx * 4;
  const float4 dj4 = *(const float4*)&dinv_s[cbase];
  #pragma unroll
  for (int i = 0; i < 4; ++i) {
    const int r = r0 + ty * 4 + i;
    const float4 w = *(const float4*)(Ab + (size_t)r * K + cbase);
    const float adi = ALPHA * dinv_s[r];
    acc[i][0] = ((r == cbase + 0) ? 1.f : 0.f) - adi * w.x * dj4.x + EPSF;
    acc[i][1] = ((r == cbase + 1) ? 1.f : 0.f) - adi * w.y * dj4.y + EPSF;
    acc[i][2] = ((r == cbase + 2) ? 1.f : 0.f) - adi * w.z * dj4.z + EPSF;
    acc[i][3] = ((r == cbase + 3) ? 1.f : 0.f) - adi * w.w * dj4.w + EPSF;
  }
}

__global__ __launch_bounds__(256) void chol_solve_kernel(
    float* __restrict__ A, const float* __restrict__ Dg,
    const int* __restrict__ anchors, float* __restrict__ out)
{
  const int b = blockIdx.x;
  float* Ab = A + (size_t)b * (K * K);
  __shared__ __align__(16) float As[64][68];
  __shared__ __align__(16) float Bs[64][68];
  __shared__ __align__(16) float Vs[64][68];   // Vs[k][c] = V[c][k], V = L11^{-1}
  __shared__ float Ld[64 * 65];
  __shared__ float ds[64];
  __shared__ __align__(16) float dinv_s[K];
  __shared__ __align__(16) float xs0[K], xs1[K];
  const int t = threadIdx.x;
  const int tx = t & 15, ty = t >> 4;

  for (int k = t; k < K; k += 256) dinv_s[k] = 1.0f / sqrtf(Dg[(size_t)b * K + k] + EPSF);
  __syncthreads();

  // =================== left-looking blocked Cholesky =====================
  for (int j = 0; j < NP; ++j) {
    const int j0 = j * NB;

    // ---- diagonal block ----
    float acc[4][4];
    init_acc(acc, Ab, dinv_s, j0, j0, tx, ty);
    for (int p = 0; p < j; ++p) {
      __syncthreads();
      stage_tile(As, Ab, j0, p * NB, t);
      __syncthreads();
      #pragma unroll 4
      for (int k = 0; k < 64; ++k) {
        const float4 a4 = *(const float4*)&As[k][ty * 4];
        const float4 b4 = *(const float4*)&As[k][tx * 4];
        const float a[4] = {a4.x, a4.y, a4.z, a4.w};
        const float bb[4] = {b4.x, b4.y, b4.z, b4.w};
        #pragma unroll
        for (int i = 0; i < 4; ++i)
          #pragma unroll
          for (int jj = 0; jj < 4; ++jj) acc[i][jj] -= a[i] * bb[jj];
      }
    }
    __syncthreads();
    #pragma unroll
    for (int i = 0; i < 4; ++i)
      #pragma unroll
      for (int jj = 0; jj < 4; ++jj) Ld[(ty * 4 + i) * 65 + tx * 4 + jj] = acc[i][jj];
    __syncthreads();

    // single-wave factor (lower triangle, right-looking) — no __syncthreads
    if (t < 64) {
      const int l = t;
      for (int k = 0; k < 64; ++k) {
        const float dk = sqrtf(Ld[k * 65 + k]);
        if (l == k) ds[k] = dk;
        const float inv = 1.0f / dk;
        float lik = 0.f;
        if (l > k) { lik = Ld[l * 65 + k] * inv; Ld[l * 65 + k] = lik; }
        __threadfence_block();
        if (l > k) {
          for (int c = k + 1; c <= l; ++c) Ld[l * 65 + c] -= lik * Ld[c * 65 + k];
        }
        __threadfence_block();
      }
      // V = L11^{-1}, column-parallel (lane = column), registers fully unrolled
      const int c = t;
      float v[64];
      #pragma unroll
      for (int r = 0; r < 64; ++r) {
        float s = (r == c) ? 1.0f : 0.0f;
        #pragma unroll
        for (int i = 0; i < 64; ++i) {
          if (i < r) s -= Ld[r * 65 + i] * v[i];
        }
        v[r] = (r >= c) ? (s / ds[r]) : 0.0f;
      }
      #pragma unroll
      for (int r = 0; r < 64; ++r) Vs[c][r] = v[r];   // Vs[k][c'] = V[c'][k]
    }
    __syncthreads();

    // write factored diagonal block (lower + diag) back to global
    for (int idx = t; idx < 4096; idx += 256) {
      const int r = idx >> 6, c = idx & 63;
      Ab[(size_t)(j0 + r) * K + j0 + c] = (r == c) ? ds[r] : Ld[r * 65 + c];
    }

    // ---- off-diagonal tiles of panel j ----
    for (int ib = j + 1; ib < NP; ++ib) {
      const int r0 = ib * NB;
      init_acc(acc, Ab, dinv_s, r0, j0, tx, ty);
      for (int p = 0; p < j; ++p) {
        __syncthreads();
        stage_tile(As, Ab, r0, p * NB, t);
        stage_tile(Bs, Ab, j0, p * NB, t);
        __syncthreads();
        #pragma unroll 4
        for (int k = 0; k < 64; ++k) {
          const float4 a4 = *(const float4*)&As[k][ty * 4];
          const float4 b4 = *(const float4*)&Bs[k][tx * 4];
          const float a[4] = {a4.x, a4.y, a4.z, a4.w};
          const float bb[4] = {b4.x, b4.y, b4.z, b4.w};
          #pragma unroll
          for (int i = 0; i < 4; ++i)
            #pragma unroll
            for (int jj = 0; jj < 4; ++jj) acc[i][jj] -= a[i] * bb[jj];
        }
      }
      __syncthreads();
      // As[k][r] := C[r][k]  (A-operand for C * V^T)
      #pragma unroll
      for (int i = 0; i < 4; ++i)
        #pragma unroll
        for (int jj = 0; jj < 4; ++jj) As[tx * 4 + jj][ty * 4 + i] = acc[i][jj];
      __syncthreads();
      float res[4][4] = {{0.f}};
      #pragma unroll 4
      for (int k = 0; k < 64; ++k) {
        const float4 a4 = *(const float4*)&As[k][ty * 4];
        const float4 b4 = *(const float4*)&Vs[k][tx * 4];
        const float a[4] = {a4.x, a4.y, a4.z, a4.w};
        const float bb[4] = {b4.x, b4.y, b4.z, b4.w};
        #pragma unroll
        for (int i = 0; i < 4; ++i)
          #pragma unroll
          for (int jj = 0; jj < 4; ++jj) res[i][jj] += a[i] * bb[jj];
      }
      #pragma unroll
      for (int i = 0; i < 4; ++i) {
        float4 o; o.x = res[i][0]; o.y = res[i][1]; o.z = res[i][2]; o.w = res[i][3];
        *(float4*)(Ab + (size_t)(r0 + ty * 4 + i) * K + j0 + tx * 4) = o;
      }
    }
    __syncthreads();
  }

  // ============================ solves ===================================
  const int a0 = anchors[2 * b], a1 = anchors[2 * b + 1];
  for (int k = t; k < K; k += 256) {
    xs0[k] = (k == a0) ? 1.f : 0.f;
    xs1[k] = (k == a1) ? 1.f : 0.f;
  }
  __syncthreads();

  // ---- forward: L x = y
  for (int blk = 0; blk < NP; ++blk) {
    const int R0 = blk * 64;
    if (blk > 0) {
      const int g = t >> 2, tg = t & 3;
      const int r = R0 + g;
      const float* rowp = Ab + (size_t)r * K;
      float s0 = 0.f, s1 = 0.f;
      for (int j = tg * 4; j < R0; j += 16) {
        const float4 l4 = *(const float4*)(rowp + j);
        const float4 p0 = *(const float4*)(xs0 + j);
        const float4 p1 = *(const float4*)(xs1 + j);
        s0 += l4.x*p0.x + l4.y*p0.y + l4.z*p0.z + l4.w*p0.w;
        s1 += l4.x*p1.x + l4.y*p1.y + l4.z*p1.z + l4.w*p1.w;
      }
      s0 += __shfl_down(s0, 2, 64); s0 += __shfl_down(s0, 1, 64);
      s1 += __shfl_down(s1, 2, 64); s1 += __shfl_down(s1, 1, 64);
      if (tg == 0) { xs0[r] -= s0; xs1[r] -= s1; }
    }
    for (int idx = t; idx < 4096; idx += 256) {
      const int rr = idx >> 6, cc = idx & 63;
      Ld[rr * 65 + cc] = Ab[(size_t)(R0 + rr) * K + R0 + cc];
    }
    __syncthreads();
    if (t < 64) {
      const int l = t;
      float xr0 = xs0[R0 + l], xr1 = xs1[R0 + l];
      const float invd = 1.0f / Ld[l * 65 + l];
      for (int j = 0; j < 64; ++j) {
        const float bj0 = __shfl(xr0, j, 64);
        const float bj1 = __shfl(xr1, j, 64);
        const float idj = __shfl(invd, j, 64);
        const float xj0 = bj0 * idj, xj1 = bj1 * idj;
        if (l == j) { xr0 = xj0; xr1 = xj1; }
        else if (l > j) { const float lij = Ld[l * 65 + j]; xr0 -= lij * xj0; xr1 -= lij * xj1; }
      }
      xs0[R0 + l] = xr0; xs1[R0 + l] = xr1;
    }
    __syncthreads();
  }

  // ---- backward: L^T x = z (reads lower triangle: U[r][j] = L[j][r])
  float* red0 = &As[0][0];          // 256 floats
  float* red1 = &As[0][0] + 256;    // 256 floats
  for (int blk = NP - 1; blk >= 0; --blk) {
    const int R0 = blk * 64;
    if (blk < NP - 1) {
      const int l = t & 63, jg = t >> 6;
      float s0 = 0.f, s1 = 0.f;
      for (int jj = R0 + 64 + jg; jj < K; jj += 4) {
        const float lv = Ab[(size_t)jj * K + R0 + l];
        s0 += lv * xs0[jj]; s1 += lv * xs1[jj];
      }
      red0[jg * 64 + l] = s0; red1[jg * 64 + l] = s1;
      __syncthreads();
      if (t < 64) {
        const float r0s = red0[t] + red0[64 + t] + red0[128 + t] + red0[192 + t];
        const float r1s = red1[t] + red1[64 + t] + red1[128 + t] + red1[192 + t];
        xs0[R0 + t] -= r0s; xs1[R0 + t] -= r1s;
      }
    }
    for (int idx = t; idx < 4096; idx += 256) {
      const int rr = idx >> 6, cc = idx & 63;
      Ld[rr * 65 + cc] = Ab[(size_t)(R0 + rr) * K + R0 + cc];
    }
    __syncthreads();
    if (t < 64) {
      const int l = t;
      float xr0 = xs0[R0 + l], xr1 = xs1[R0 + l];
      const float invd = 1.0f / Ld[l * 65 + l];
      for (int j = 63; j >= 0; --j) {
        const float bj0 = __shfl(xr0, j, 64);
        const float bj1 = __shfl(xr1, j, 64);
        const float idj = __shfl(invd, j, 64);
        const float xj0 = bj0 * idj, xj1 = bj1 * idj;
        if (l == j) { xr0 = xj0; xr1 = xj1; }
        else if (l < j) { const float u = Ld[j * 65 + l]; xr0 -= u * xj0; xr1 -= u * xj1; }
      }
      xs0[R0 + l] = xr0; xs1[R0 + l] = xr1;
    }
    __syncthreads();
  }

  for (int k = t; k < K; k += 256) {
    out[((size_t)b * K + k) * 2 + 0] = xs0[k];
    out[((size_t)b * K + k) * 2 + 1] = xs1[k];
  }
}

// ==========================================================================
extern "C" void kernel_launch(void* const* d_in, const int* in_sizes, int n_in,
                              void* d_out, int out_size, void* d_ws, size_t ws_size,
                              hipStream_t stream) {
  const float* F = (const float*)d_in[0];   // [B,K,D]
  const float* Q = (const float*)d_in[1];   // [B,D]
  float* out = (float*)d_out;               // [B,K,2]
  const int B = in_sizes[1] / D;            // 128

  float* Abuf = (float*)d_ws;                          // B*K*K
  float* Dg   = Abuf + (size_t)B * K * K;              // B*K (degree sums)
  int*   anch = (int*)(Dg + (size_t)B * K);            // B*2

  hipMemsetAsync(Dg, 0, (size_t)B * K * sizeof(float), stream);
  anchors_kernel<<<B, 256, 0, stream>>>(F, Q, anch);
  gram_kernel<<<dim3(NP * (NP + 1) / 2, 1, B), 256, 0, stream>>>(F, Abuf, Dg);
  chol_solve_kernel<<<B, 256, 0, stream>>>(Abuf, Dg, anch, out);
}

// Round 3
// 609.824 us; speedup vs baseline: 3.8952x; 3.6881x over previous
//
#include <hip/hip_runtime.h>
#include <math.h>

static constexpr int K = 512;
static constexpr int D = 256;
static constexpr int NIT = 6;                 // Neumann terms (rate ~0.015/term)
static constexpr float ALPHA = 0.99f;
static constexpr float EPSF  = 2.2204460492503131e-16f;

// ============================ anchors =====================================
__global__ __launch_bounds__(256) void anchors_kernel(
    const float* __restrict__ F, const float* __restrict__ Q, int* __restrict__ anchors)
{
  const int b = blockIdx.x;
  const float* Fb = F + (size_t)b * (K * D);
  __shared__ __align__(16) float qs[D];
  __shared__ float sim[K];
  __shared__ float rv[256];
  __shared__ int   ri[256];
  const int t = threadIdx.x;
  const int wave = t >> 6, lane = t & 63;

  qs[t] = Q[(size_t)b * D + t];
  __syncthreads();

  for (int k = wave; k < K; k += 4) {
    const float4 f4 = *(const float4*)(Fb + (size_t)k * D + lane * 4);
    const float4 q4 = *(const float4*)(qs + lane * 4);
    float p = f4.x*q4.x + f4.y*q4.y + f4.z*q4.z + f4.w*q4.w;
    #pragma unroll
    for (int off = 32; off >= 1; off >>= 1) p += __shfl_down(p, off, 64);
    if (lane == 0) sim[k] = p;
  }
  __syncthreads();

  {
    float v0 = sim[t]; int i0 = t;
    float v1 = sim[t + 256];
    if (v1 < v0) { v0 = v1; i0 = t + 256; }
    rv[t] = v0; ri[t] = i0;
  }
  __syncthreads();
  for (int s = 128; s > 0; s >>= 1) {
    if (t < s) {
      float ov = rv[t + s]; int oi = ri[t + s];
      if (ov < rv[t] || (ov == rv[t] && oi < ri[t])) { rv[t] = ov; ri[t] = oi; }
    }
    __syncthreads();
  }
  const int a0 = ri[0];
  __syncthreads();

  qs[t] = Fb[(size_t)a0 * D + t];
  __syncthreads();
  for (int k = wave; k < K; k += 4) {
    const float4 f4 = *(const float4*)(Fb + (size_t)k * D + lane * 4);
    const float4 q4 = *(const float4*)(qs + lane * 4);
    float p = f4.x*q4.x + f4.y*q4.y + f4.z*q4.z + f4.w*q4.w;
    #pragma unroll
    for (int off = 32; off >= 1; off >>= 1) p += __shfl_down(p, off, 64);
    if (lane == 0) sim[k] = fmaxf(sim[k], p);
  }
  __syncthreads();

  {
    float v0 = sim[t]; int i0 = t;
    float v1 = sim[t + 256];
    if (v1 < v0) { v0 = v1; i0 = t + 256; }
    rv[t] = v0; ri[t] = i0;
  }
  __syncthreads();
  for (int s = 128; s > 0; s >>= 1) {
    if (t < s) {
      float ov = rv[t + s]; int oi = ri[t + s];
      if (ov < rv[t] || (ov == rv[t] && oi < ri[t])) { rv[t] = ov; ri[t] = oi; }
    }
    __syncthreads();
  }
  const int a1 = ri[0];
  if (t == 0) { anchors[2 * b] = a0; anchors[2 * b + 1] = a1; }
}

// ===== gram: W = exp(F F^T) full (lower computed, upper mirrored), degrees =====
__global__ __launch_bounds__(256) void gram_kernel(
    const float* __restrict__ F, float* __restrict__ W, float* __restrict__ Dg)
{
  const int b  = blockIdx.z;
  const int ti = blockIdx.x;                   // 0..35 lower-tri tile id
  int bi = 0; while ((bi + 1) * (bi + 2) / 2 <= ti) ++bi;
  const int bj = ti - bi * (bi + 1) / 2;
  const int r0 = bi * 64, c0 = bj * 64;
  const float* Fb = F + (size_t)b * (K * D);
  float* Wb = W + (size_t)b * (K * K);

  __shared__ __align__(16) float As[64][68];   // [d][row]
  __shared__ __align__(16) float Bs[64][68];   // [d][col]
  __shared__ float csum[16][68];
  const int t = threadIdx.x;
  const int tx = t & 15, ty = t >> 4;
  const int row = t >> 2, g = t & 3;           // loader mapping (conflict-free)

  float acc[4][4] = {{0.f}};
  float (*Bsel)[68] = (bi == bj) ? As : Bs;

  for (int kk = 0; kk < D; kk += 64) {
    __syncthreads();
    {
      const float* srcA = Fb + (size_t)(r0 + row) * D + kk + g * 4;
      #pragma unroll
      for (int q = 0; q < 4; ++q) {
        const float4 v = *(const float4*)(srcA + q * 16);
        const int d = g * 4 + q * 16;
        As[d+0][row] = v.x; As[d+1][row] = v.y; As[d+2][row] = v.z; As[d+3][row] = v.w;
      }
      if (bi != bj) {
        const float* srcB = Fb + (size_t)(c0 + row) * D + kk + g * 4;
        #pragma unroll
        for (int q = 0; q < 4; ++q) {
          const float4 v = *(const float4*)(srcB + q * 16);
          const int d = g * 4 + q * 16;
          Bs[d+0][row] = v.x; Bs[d+1][row] = v.y; Bs[d+2][row] = v.z; Bs[d+3][row] = v.w;
        }
      }
    }
    __syncthreads();
    #pragma unroll 4
    for (int k = 0; k < 64; ++k) {
      const float4 a4 = *(const float4*)&As[k][ty * 4];
      const float4 b4 = *(const float4*)&Bsel[k][tx * 4];
      const float a[4] = {a4.x, a4.y, a4.z, a4.w};
      const float bb[4] = {b4.x, b4.y, b4.z, b4.w};
      #pragma unroll
      for (int i = 0; i < 4; ++i)
        #pragma unroll
        for (int j = 0; j < 4; ++j) acc[i][j] += a[i] * bb[j];
    }
  }

  // epilogue: exp, zero diag, store lower tile, degree sums
  const int gc0 = c0 + tx * 4;
  float colp[4] = {0.f, 0.f, 0.f, 0.f};
  float rowp_[4];
  float oe[4][4];
  #pragma unroll
  for (int i = 0; i < 4; ++i) {
    const int gr = r0 + ty * 4 + i;
    float4 o;
    o.x = (gr == gc0 + 0) ? 0.f : expf(acc[i][0]);
    o.y = (gr == gc0 + 1) ? 0.f : expf(acc[i][1]);
    o.z = (gr == gc0 + 2) ? 0.f : expf(acc[i][2]);
    o.w = (gr == gc0 + 3) ? 0.f : expf(acc[i][3]);
    *(float4*)(Wb + (size_t)gr * K + gc0) = o;
    oe[i][0] = o.x; oe[i][1] = o.y; oe[i][2] = o.z; oe[i][3] = o.w;
    rowp_[i] = o.x + o.y + o.z + o.w;
    colp[0] += o.x; colp[1] += o.y; colp[2] += o.z; colp[3] += o.w;
  }
  #pragma unroll
  for (int i = 0; i < 4; ++i) {
    float v = rowp_[i];
    v += __shfl_down(v, 8, 16); v += __shfl_down(v, 4, 16);
    v += __shfl_down(v, 2, 16); v += __shfl_down(v, 1, 16);
    if (tx == 0) atomicAdd(&Dg[(size_t)b * K + r0 + ty * 4 + i], v);
  }
  if (bi != bj) {   // symmetric contribution to columns' degrees
    csum[ty][tx * 4 + 0] = colp[0]; csum[ty][tx * 4 + 1] = colp[1];
    csum[ty][tx * 4 + 2] = colp[2]; csum[ty][tx * 4 + 3] = colp[3];
    __syncthreads();
    if (t < 64) {
      float s = 0.f;
      #pragma unroll
      for (int y = 0; y < 16; ++y) s += csum[y][t];
      atomicAdd(&Dg[(size_t)b * K + c0 + t], s);
    }
    // mirror: write exp'd tile transposed into the upper triangle
    __syncthreads();                 // As no longer needed by k-loop
    #pragma unroll
    for (int i = 0; i < 4; ++i)
      #pragma unroll
      for (int j = 0; j < 4; ++j) As[tx * 4 + j][ty * 4 + i] = oe[i][j];
    __syncthreads();
    for (int idx = t; idx < 4096; idx += 256) {
      const int cc = idx >> 6, rr = idx & 63;
      Wb[(size_t)(c0 + cc) * K + r0 + rr] = As[cc][rr];
    }
  }
}

// ====== Neumann + Sherman-Morrison solve:  x = sum (aR)^n y + a/(1-a) v (v.y) ======
// R = S - vv^T, S = D^{-1/2} W D^{-1/2}, v = sqrt(d)/||sqrt(d)||  (Sv = v exactly)
__global__ __launch_bounds__(256) void neumann_solve_kernel(
    const float* __restrict__ W, const float* __restrict__ Dg,
    const int* __restrict__ anchors, float* __restrict__ out)
{
  const int b = blockIdx.x;
  const float* Wb = W + (size_t)b * (K * K);
  __shared__ __align__(16) float dinv_s[K], v_s[K];
  __shared__ __align__(16) float u0[K], u1[K], z0[K], z1[K], zn0[K], zn1[K];
  __shared__ float redbuf[8];
  const int t = threadIdx.x;
  const int wave = t >> 6, lane = t & 63;

  // degrees -> dinv, v (unnormalized), total degree
  float dpart = 0.f;
  for (int k = t; k < K; k += 256) {
    const float d = Dg[(size_t)b * K + k];
    dinv_s[k] = 1.0f / sqrtf(d + EPSF);
    v_s[k] = sqrtf(d);
    dpart += d;
  }
  #pragma unroll
  for (int off = 32; off >= 1; off >>= 1) dpart += __shfl_down(dpart, off, 64);
  if (lane == 0) redbuf[wave] = dpart;
  __syncthreads();
  const float vnorm = 1.0f / sqrtf(redbuf[0] + redbuf[1] + redbuf[2] + redbuf[3]);
  __syncthreads();
  for (int k = t; k < K; k += 256) v_s[k] *= vnorm;

  const int a0 = anchors[2 * b], a1 = anchors[2 * b + 1];
  for (int k = t; k < K; k += 256) {
    const float y0 = (k == a0) ? 1.f : 0.f;
    const float y1 = (k == a1) ? 1.f : 0.f;
    u0[k] = y0; u1[k] = y1;    // u holds current term w_n (starts at y)
    z0[k] = y0; z1[k] = y1;    // z accumulates the Neumann sum
  }
  __syncthreads();

  for (int it = 0; it < NIT; ++it) {
    // s = v^T w
    float p0 = 0.f, p1 = 0.f;
    for (int k = t; k < K; k += 256) { p0 += v_s[k] * u0[k]; p1 += v_s[k] * u1[k]; }
    #pragma unroll
    for (int off = 32; off >= 1; off >>= 1) {
      p0 += __shfl_down(p0, off, 64); p1 += __shfl_down(p1, off, 64);
    }
    if (lane == 0) { redbuf[wave] = p0; redbuf[4 + wave] = p1; }
    __syncthreads();
    const float s0 = redbuf[0] + redbuf[1] + redbuf[2] + redbuf[3];
    const float s1 = redbuf[4] + redbuf[5] + redbuf[6] + redbuf[7];
    // u := dinv o w   (v^T reads completed at the sync above)
    for (int k = t; k < K; k += 256) { u0[k] *= dinv_s[k]; u1[k] *= dinv_s[k]; }
    __syncthreads();
    // zn = W u  (row-GEMV: 4 rows/wave-step, 16 lanes per row)
    const int sub = lane >> 4, cg = lane & 15;
    for (int s = 0; s < 32; ++s) {
      const int r = s * 16 + wave * 4 + sub;
      const float* wrow = Wb + (size_t)r * K;
      float q0 = 0.f, q1 = 0.f;
      #pragma unroll
      for (int q = 0; q < 8; ++q) {
        const int c = q * 64 + cg * 4;
        const float4 wv = *(const float4*)(wrow + c);
        const float4 a  = *(const float4*)(u0 + c);
        const float4 bb = *(const float4*)(u1 + c);
        q0 += wv.x*a.x  + wv.y*a.y  + wv.z*a.z  + wv.w*a.w;
        q1 += wv.x*bb.x + wv.y*bb.y + wv.z*bb.z + wv.w*bb.w;
      }
      #pragma unroll
      for (int off = 8; off >= 1; off >>= 1) {
        q0 += __shfl_down(q0, off, 16); q1 += __shfl_down(q1, off, 16);
      }
      if (cg == 0) { zn0[r] = q0; zn1[r] = q1; }
    }
    __syncthreads();
    // w_{n+1} = alpha * (dinv o zn - v * s);  z += w_{n+1}
    for (int k = t; k < K; k += 256) {
      const float w0n = ALPHA * (dinv_s[k] * zn0[k] - v_s[k] * s0);
      const float w1n = ALPHA * (dinv_s[k] * zn1[k] - v_s[k] * s1);
      u0[k] = w0n; u1[k] = w1n;
      z0[k] += w0n; z1[k] += w1n;
    }
    __syncthreads();
  }

  // rank-1 exact correction: + alpha/(1-alpha) * v * v[anchor]
  const float c99 = ALPHA / (1.0f - ALPHA);
  const float cv0 = c99 * v_s[a0], cv1 = c99 * v_s[a1];
  float2* out2 = (float2*)out;
  for (int k = t; k < K; k += 256) {
    float2 o;
    o.x = z0[k] + cv0 * v_s[k];
    o.y = z1[k] + cv1 * v_s[k];
    out2[(size_t)b * K + k] = o;
  }
}

// ==========================================================================
extern "C" void kernel_launch(void* const* d_in, const int* in_sizes, int n_in,
                              void* d_out, int out_size, void* d_ws, size_t ws_size,
                              hipStream_t stream) {
  const float* F = (const float*)d_in[0];   // [B,K,D]
  const float* Q = (const float*)d_in[1];   // [B,D]
  float* out = (float*)d_out;               // [B,K,2]
  const int B = in_sizes[1] / D;            // 128

  float* Wbuf = (float*)d_ws;                          // B*K*K
  float* Dg   = Wbuf + (size_t)B * K * K;              // B*K (degree sums)
  int*   anch = (int*)(Dg + (size_t)B * K);            // B*2

  hipMemsetAsync(Dg, 0, (size_t)B * K * sizeof(float), stream);
  anchors_kernel<<<B, 256, 0, stream>>>(F, Q, anch);
  gram_kernel<<<dim3(36, 1, B), 256, 0, stream>>>(F, Wbuf, Dg);
  neumann_solve_kernel<<<B, 256, 0, stream>>>(Wbuf, Dg, anch, out);
}

// Round 4
// 359.852 us; speedup vs baseline: 6.6010x; 1.6946x over previous
//
#include <hip/hip_runtime.h>
#include <math.h>

static constexpr int K = 512;
static constexpr int D = 256;
static constexpr float ALPHA = 0.99f;
static constexpr float EPSF  = 2.2204460492503131e-16f;

typedef __bf16 bf16x8 __attribute__((ext_vector_type(8)));
typedef float floatx4 __attribute__((ext_vector_type(4)));

__device__ __forceinline__ bf16x8 cvt8(const float4 a, const float4 b) {
  bf16x8 o;
  o[0] = (__bf16)a.x; o[1] = (__bf16)a.y; o[2] = (__bf16)a.z; o[3] = (__bf16)a.w;
  o[4] = (__bf16)b.x; o[5] = (__bf16)b.y; o[6] = (__bf16)b.z; o[7] = (__bf16)b.w;
  return o;
}

// ============================ anchors =====================================
__global__ __launch_bounds__(256) void anchors_kernel(
    const float* __restrict__ F, const float* __restrict__ Q, int* __restrict__ anchors)
{
  const int b = blockIdx.x;
  const float* Fb = F + (size_t)b * (K * D);
  __shared__ __align__(16) float qs[D];
  __shared__ float sim[K];
  __shared__ float rv[256];
  __shared__ int   ri[256];
  const int t = threadIdx.x;
  const int wave = t >> 6, lane = t & 63;

  qs[t] = Q[(size_t)b * D + t];
  __syncthreads();

  for (int k = wave; k < K; k += 4) {
    const float4 f4 = *(const float4*)(Fb + (size_t)k * D + lane * 4);
    const float4 q4 = *(const float4*)(qs + lane * 4);
    float p = f4.x*q4.x + f4.y*q4.y + f4.z*q4.z + f4.w*q4.w;
    #pragma unroll
    for (int off = 32; off >= 1; off >>= 1) p += __shfl_down(p, off, 64);
    if (lane == 0) sim[k] = p;
  }
  __syncthreads();

  {
    float v0 = sim[t]; int i0 = t;
    float v1 = sim[t + 256];
    if (v1 < v0) { v0 = v1; i0 = t + 256; }
    rv[t] = v0; ri[t] = i0;
  }
  __syncthreads();
  for (int s = 128; s > 0; s >>= 1) {
    if (t < s) {
      float ov = rv[t + s]; int oi = ri[t + s];
      if (ov < rv[t] || (ov == rv[t] && oi < ri[t])) { rv[t] = ov; ri[t] = oi; }
    }
    __syncthreads();
  }
  const int a0 = ri[0];
  __syncthreads();

  qs[t] = Fb[(size_t)a0 * D + t];
  __syncthreads();
  for (int k = wave; k < K; k += 4) {
    const float4 f4 = *(const float4*)(Fb + (size_t)k * D + lane * 4);
    const float4 q4 = *(const float4*)(qs + lane * 4);
    float p = f4.x*q4.x + f4.y*q4.y + f4.z*q4.z + f4.w*q4.w;
    #pragma unroll
    for (int off = 32; off >= 1; off >>= 1) p += __shfl_down(p, off, 64);
    if (lane == 0) sim[k] = fmaxf(sim[k], p);
  }
  __syncthreads();

  {
    float v0 = sim[t]; int i0 = t;
    float v1 = sim[t + 256];
    if (v1 < v0) { v0 = v1; i0 = t + 256; }
    rv[t] = v0; ri[t] = i0;
  }
  __syncthreads();
  for (int s = 128; s > 0; s >>= 1) {
    if (t < s) {
      float ov = rv[t + s]; int oi = ri[t + s];
      if (ov < rv[t] || (ov == rv[t] && oi < ri[t])) { rv[t] = ov; ri[t] = oi; }
    }
    __syncthreads();
  }
  const int a1 = ri[0];
  if (t == 0) { anchors[2 * b] = a0; anchors[2 * b + 1] = a1; }
}

// ======= gram via bf16 MFMA: W = exp(F F^T), zero diag, + row degrees =====
// Block computes a 128x128 tile. Wave w: rows [w*32, w*32+32) x 128 cols.
__global__ __launch_bounds__(256) void gram_mfma_kernel(
    const float* __restrict__ F, float* __restrict__ W, float* __restrict__ Dg)
{
  const int b  = blockIdx.z;
  const int r0 = blockIdx.y * 128;
  const int c0 = blockIdx.x * 128;
  const float* Fb = F + (size_t)b * (K * D);
  float* Wb = W + (size_t)b * (K * K);

  __shared__ __bf16 Asb[128][40];   // [row][k], stride 40 bf16 = 80 B (2-way max)
  __shared__ __bf16 Bsb[128][40];
  const int t = threadIdx.x;
  const int wave = t >> 6, lane = t & 63;
  const int quad = lane >> 4, l15 = lane & 15;

  floatx4 acc[2][8];
  #pragma unroll
  for (int i = 0; i < 2; ++i)
    #pragma unroll
    for (int j = 0; j < 8; ++j) acc[i][j] = (floatx4){0.f, 0.f, 0.f, 0.f};

  const int srow = t >> 1, skh = (t & 1) * 16;
  for (int kk = 0; kk < D; kk += 32) {
    __syncthreads();
    {
      const float* sa = Fb + (size_t)(r0 + srow) * D + kk + skh;
      const float4 a0 = *(const float4*)(sa + 0),  a1 = *(const float4*)(sa + 4);
      const float4 a2 = *(const float4*)(sa + 8),  a3 = *(const float4*)(sa + 12);
      *(bf16x8*)&Asb[srow][skh]     = cvt8(a0, a1);
      *(bf16x8*)&Asb[srow][skh + 8] = cvt8(a2, a3);
      const float* sb = Fb + (size_t)(c0 + srow) * D + kk + skh;
      const float4 b0 = *(const float4*)(sb + 0),  b1 = *(const float4*)(sb + 4);
      const float4 b2 = *(const float4*)(sb + 8),  b3 = *(const float4*)(sb + 12);
      *(bf16x8*)&Bsb[srow][skh]     = cvt8(b0, b1);
      *(bf16x8*)&Bsb[srow][skh + 8] = cvt8(b2, b3);
    }
    __syncthreads();
    bf16x8 af[2], bf[8];
    #pragma unroll
    for (int tm = 0; tm < 2; ++tm)
      af[tm] = *(bf16x8*)&Asb[wave * 32 + tm * 16 + l15][quad * 8];
    #pragma unroll
    for (int tn = 0; tn < 8; ++tn)
      bf[tn] = *(bf16x8*)&Bsb[tn * 16 + l15][quad * 8];
    #pragma unroll
    for (int tm = 0; tm < 2; ++tm)
      #pragma unroll
      for (int tn = 0; tn < 8; ++tn)
        acc[tm][tn] = __builtin_amdgcn_mfma_f32_16x16x32_bf16(af[tm], bf[tn], acc[tm][tn], 0, 0, 0);
  }

  // epilogue: exp, zero diag, store, row-degree atomics
  float rs[2][4] = {{0.f, 0.f, 0.f, 0.f}, {0.f, 0.f, 0.f, 0.f}};
  #pragma unroll
  for (int tm = 0; tm < 2; ++tm) {
    const int grb = r0 + wave * 32 + tm * 16 + quad * 4;
    #pragma unroll
    for (int tn = 0; tn < 8; ++tn) {
      const int gc = c0 + tn * 16 + l15;
      #pragma unroll
      for (int r = 0; r < 4; ++r) {
        const int gr = grb + r;
        const float wv = (gr == gc) ? 0.f : __expf(acc[tm][tn][r]);
        Wb[(size_t)gr * K + gc] = wv;
        rs[tm][r] += wv;
      }
    }
  }
  #pragma unroll
  for (int tm = 0; tm < 2; ++tm)
    #pragma unroll
    for (int r = 0; r < 4; ++r) {
      float v = rs[tm][r];
      v += __shfl_xor(v, 1, 64); v += __shfl_xor(v, 2, 64);
      v += __shfl_xor(v, 4, 64); v += __shfl_xor(v, 8, 64);
      if (l15 == 0)
        atomicAdd(&Dg[(size_t)b * K + r0 + wave * 32 + tm * 16 + quad * 4 + r], v);
    }
}

// ===== one Neumann term per launch: w' = a(dinv o (W (dinv o w)) - v (v.w)) =====
// mode 0: w = one-hot y (no GEMV: 2 column reads); writes u_out, z = y + w'
// mode 1: GEMV; u_out = w', z += w'
// mode 2: GEMV; out = z + w' + a/(1-a) * v * v[anchor]
__global__ __launch_bounds__(256) void iter_kernel(
    const float* __restrict__ W, const float* __restrict__ Dg,
    const int* __restrict__ anchors,
    const float* __restrict__ u_in, float* __restrict__ u_out,
    float* __restrict__ z, float* __restrict__ out, const int mode)
{
  const int b = blockIdx.y;
  const int r0 = blockIdx.x * 128;
  const float* Wb = W + (size_t)b * (K * K);
  __shared__ __align__(16) float dinv_s[K], sqd_s[K], t0[K], t1[K];
  __shared__ float red[12];
  const int t = threadIdx.x;
  const int wave = t >> 6, lane = t & 63;
  const int a0 = anchors[2 * b], a1 = anchors[2 * b + 1];

  float dsum = 0.f, p0 = 0.f, p1 = 0.f;
  if (mode == 0) {
    for (int k = t; k < K; k += 256) {
      const float d = Dg[(size_t)b * K + k];
      const float sq = sqrtf(d);
      const float di = 1.0f / sqrtf(d + EPSF);
      dinv_s[k] = di; sqd_s[k] = sq; dsum += d;
      t0[k] = (k == a0) ? di : 0.f;
      t1[k] = (k == a1) ? di : 0.f;
    }
  } else {
    const float* ui0 = u_in + (size_t)b * 2 * K;
    const float* ui1 = ui0 + K;
    for (int k = t; k < K; k += 256) {
      const float d = Dg[(size_t)b * K + k];
      const float sq = sqrtf(d);
      const float di = 1.0f / sqrtf(d + EPSF);
      dinv_s[k] = di; sqd_s[k] = sq; dsum += d;
      const float u0v = ui0[k], u1v = ui1[k];
      t0[k] = di * u0v; t1[k] = di * u1v;
      p0 += sq * u0v; p1 += sq * u1v;
    }
  }
  #pragma unroll
  for (int off = 32; off >= 1; off >>= 1) {
    dsum += __shfl_down(dsum, off, 64);
    p0   += __shfl_down(p0,   off, 64);
    p1   += __shfl_down(p1,   off, 64);
  }
  if (lane == 0) { red[wave] = dsum; red[4 + wave] = p0; red[8 + wave] = p1; }
  __syncthreads();
  const float vn = 1.0f / sqrtf(red[0] + red[1] + red[2] + red[3]);
  float s0, s1;
  if (mode == 0) { s0 = vn * sqd_s[a0]; s1 = vn * sqd_s[a1]; }
  else { s0 = vn * (red[4] + red[5] + red[6] + red[7]);
         s1 = vn * (red[8] + red[9] + red[10] + red[11]); }

  float* uo0 = u_out + (size_t)b * 2 * K;
  float* uo1 = uo0 + K;
  float2* zb = (float2*)(z + (size_t)b * K * 2);
  float2* ob = (float2*)(out + (size_t)b * K * 2);
  const float c99 = ALPHA / (1.0f - ALPHA);
  const float cva0 = c99 * vn * sqd_s[a0];
  const float cva1 = c99 * vn * sqd_s[a1];
  const int sub = lane >> 4, cg = lane & 15;

  for (int pass = 0; pass < 8; ++pass) {
    const int r = r0 + wave * 32 + pass * 4 + sub;
    float q0 = 0.f, q1 = 0.f;
    if (mode == 0) {
      if (cg == 0) {
        q0 = Wb[(size_t)r * K + a0] * dinv_s[a0];
        q1 = Wb[(size_t)r * K + a1] * dinv_s[a1];
      }
    } else {
      const float* wrow = Wb + (size_t)r * K;
      #pragma unroll
      for (int q = 0; q < 8; ++q) {
        const int c = q * 64 + cg * 4;
        const float4 wv = *(const float4*)(wrow + c);
        const float4 x0 = *(const float4*)(t0 + c);
        const float4 x1 = *(const float4*)(t1 + c);
        q0 += wv.x*x0.x + wv.y*x0.y + wv.z*x0.z + wv.w*x0.w;
        q1 += wv.x*x1.x + wv.y*x1.y + wv.z*x1.z + wv.w*x1.w;
      }
      q0 += __shfl_xor(q0, 1, 64); q0 += __shfl_xor(q0, 2, 64);
      q0 += __shfl_xor(q0, 4, 64); q0 += __shfl_xor(q0, 8, 64);
      q1 += __shfl_xor(q1, 1, 64); q1 += __shfl_xor(q1, 2, 64);
      q1 += __shfl_xor(q1, 4, 64); q1 += __shfl_xor(q1, 8, 64);
    }
    if (cg == 0) {
      const float di = dinv_s[r];
      const float vr = vn * sqd_s[r];
      const float w0n = ALPHA * (di * q0 - vr * s0);
      const float w1n = ALPHA * (di * q1 - vr * s1);
      if (mode == 0) {
        uo0[r] = w0n; uo1[r] = w1n;
        float2 zv;
        zv.x = ((r == a0) ? 1.f : 0.f) + w0n;
        zv.y = ((r == a1) ? 1.f : 0.f) + w1n;
        zb[r] = zv;
      } else if (mode == 1) {
        uo0[r] = w0n; uo1[r] = w1n;
        float2 zv = zb[r]; zv.x += w0n; zv.y += w1n; zb[r] = zv;
      } else {
        const float2 zv = zb[r];
        float2 o;
        o.x = zv.x + w0n + cva0 * vr;
        o.y = zv.y + w1n + cva1 * vr;
        ob[r] = o;
      }
    }
  }
}

// ==========================================================================
extern "C" void kernel_launch(void* const* d_in, const int* in_sizes, int n_in,
                              void* d_out, int out_size, void* d_ws, size_t ws_size,
                              hipStream_t stream) {
  const float* F = (const float*)d_in[0];   // [B,K,D]
  const float* Q = (const float*)d_in[1];   // [B,D]
  float* out = (float*)d_out;               // [B,K,2]
  const int B = in_sizes[1] / D;            // 128

  float* Wbuf = (float*)d_ws;                          // B*K*K
  float* Dg   = Wbuf + (size_t)B * K * K;              // B*K
  float* uA   = Dg + (size_t)B * K;                    // B*2*K
  float* uB   = uA + (size_t)B * 2 * K;                // B*2*K
  float* zbuf = uB + (size_t)B * 2 * K;                // B*K*2
  int*   anch = (int*)(zbuf + (size_t)B * K * 2);      // B*2

  hipMemsetAsync(Dg, 0, (size_t)B * K * sizeof(float), stream);
  anchors_kernel<<<B, 256, 0, stream>>>(F, Q, anch);
  gram_mfma_kernel<<<dim3(4, 4, B), 256, 0, stream>>>(F, Wbuf, Dg);
  iter_kernel<<<dim3(4, B), 256, 0, stream>>>(Wbuf, Dg, anch, uB, uA, zbuf, out, 0);
  iter_kernel<<<dim3(4, B), 256, 0, stream>>>(Wbuf, Dg, anch, uA, uB, zbuf, out, 1);
  iter_kernel<<<dim3(4, B), 256, 0, stream>>>(Wbuf, Dg, anch, uB, uA, zbuf, out, 2);
}

// Round 5
// 238.759 us; speedup vs baseline: 9.9489x; 1.5072x over previous
//
#include <hip/hip_runtime.h>
#include <math.h>

static constexpr int K = 512;
static constexpr int D = 256;
static constexpr float ALPHA = 0.99f;
static constexpr float EPSF  = 2.2204460492503131e-16f;

typedef __bf16 bf16x8 __attribute__((ext_vector_type(8)));
typedef float floatx4 __attribute__((ext_vector_type(4)));

__device__ __forceinline__ bf16x8 cvt8(const float4 a, const float4 b) {
  bf16x8 o;
  o[0] = (__bf16)a.x; o[1] = (__bf16)a.y; o[2] = (__bf16)a.z; o[3] = (__bf16)a.w;
  o[4] = (__bf16)b.x; o[5] = (__bf16)b.y; o[6] = (__bf16)b.z; o[7] = (__bf16)b.w;
  return o;
}

// ordered-float encoding: monotone map float -> u32 (for atomicMin argmin)
__device__ __forceinline__ unsigned int f2o(float f) {
  unsigned int u = __float_as_uint(f);
  return (u & 0x80000000u) ? ~u : (u | 0x80000000u);
}

// ====== anchors round 1: sim1 = F.q, fused grid-wide argmin (u64 atomicMin) ======
__global__ __launch_bounds__(256) void sim1_kernel(
    const float* __restrict__ F, const float* __restrict__ Q,
    float* __restrict__ simbuf, unsigned long long* __restrict__ m0)
{
  const int b = blockIdx.y;
  const int r0 = blockIdx.x * 64;
  const float* Fb = F + (size_t)b * (K * D);
  __shared__ __align__(16) float qs[D];
  const int t = threadIdx.x;
  const int wave = t >> 6, lane = t & 63;
  const int sub = lane >> 4, cg = lane & 15;
  qs[t] = Q[(size_t)b * D + t];
  __syncthreads();

  unsigned long long best = ~0ULL;
  #pragma unroll
  for (int pass = 0; pass < 4; ++pass) {
    const int r = r0 + pass * 16 + wave * 4 + sub;
    const float* fr = Fb + (size_t)r * D;
    float p = 0.f;
    #pragma unroll
    for (int q = 0; q < 4; ++q) {
      const int c = q * 64 + cg * 4;
      const float4 fv = *(const float4*)(fr + c);
      const float4 qv = *(const float4*)(qs + c);
      p += fv.x*qv.x + fv.y*qv.y + fv.z*qv.z + fv.w*qv.w;
    }
    p += __shfl_xor(p, 1, 64); p += __shfl_xor(p, 2, 64);
    p += __shfl_xor(p, 4, 64); p += __shfl_xor(p, 8, 64);
    if (cg == 0) {
      simbuf[(size_t)b * K + r] = p;
      const unsigned long long e =
          ((unsigned long long)f2o(p) << 32) | (unsigned int)r;
      best = (e < best) ? e : best;
    }
  }
  if (cg == 0) atomicMin(m0 + b, best);
}

// ====== anchors round 2: sim2 = F.f_a0, max with sim1, argmin ======
__global__ __launch_bounds__(256) void sim2_kernel(
    const float* __restrict__ F, const float* __restrict__ simbuf,
    const unsigned long long* __restrict__ m0, unsigned long long* __restrict__ m1)
{
  const int b = blockIdx.y;
  const int r0 = blockIdx.x * 64;
  const int a0 = (int)(m0[b] & 0xffffffffu);
  const float* Fb = F + (size_t)b * (K * D);
  __shared__ __align__(16) float qs[D];
  const int t = threadIdx.x;
  const int wave = t >> 6, lane = t & 63;
  const int sub = lane >> 4, cg = lane & 15;
  qs[t] = Fb[(size_t)a0 * D + t];
  __syncthreads();

  unsigned long long best = ~0ULL;
  #pragma unroll
  for (int pass = 0; pass < 4; ++pass) {
    const int r = r0 + pass * 16 + wave * 4 + sub;
    const float* fr = Fb + (size_t)r * D;
    float p = 0.f;
    #pragma unroll
    for (int q = 0; q < 4; ++q) {
      const int c = q * 64 + cg * 4;
      const float4 fv = *(const float4*)(fr + c);
      const float4 qv = *(const float4*)(qs + c);
      p += fv.x*qv.x + fv.y*qv.y + fv.z*qv.z + fv.w*qv.w;
    }
    p += __shfl_xor(p, 1, 64); p += __shfl_xor(p, 2, 64);
    p += __shfl_xor(p, 4, 64); p += __shfl_xor(p, 8, 64);
    if (cg == 0) {
      const float m = fmaxf(simbuf[(size_t)b * K + r], p);
      const unsigned long long e =
          ((unsigned long long)f2o(m) << 32) | (unsigned int)r;
      best = (e < best) ? e : best;
    }
  }
  if (cg == 0) atomicMin(m1 + b, best);
}

// ======= gram via bf16 MFMA: W = exp(F F^T), zero diag, + row degrees =====
__global__ __launch_bounds__(256) void gram_mfma_kernel(
    const float* __restrict__ F, float* __restrict__ W, float* __restrict__ Dg)
{
  const int b  = blockIdx.z;
  const int r0 = blockIdx.y * 128;
  const int c0 = blockIdx.x * 128;
  const float* Fb = F + (size_t)b * (K * D);
  float* Wb = W + (size_t)b * (K * K);

  __shared__ __bf16 Asb[128][40];   // [row][k], stride 40 bf16 = 80 B (2-way max)
  __shared__ __bf16 Bsb[128][40];
  const int t = threadIdx.x;
  const int wave = t >> 6, lane = t & 63;
  const int quad = lane >> 4, l15 = lane & 15;

  floatx4 acc[2][8];
  #pragma unroll
  for (int i = 0; i < 2; ++i)
    #pragma unroll
    for (int j = 0; j < 8; ++j) acc[i][j] = (floatx4){0.f, 0.f, 0.f, 0.f};

  const int srow = t >> 1, skh = (t & 1) * 16;
  for (int kk = 0; kk < D; kk += 32) {
    __syncthreads();
    {
      const float* sa = Fb + (size_t)(r0 + srow) * D + kk + skh;
      const float4 a0 = *(const float4*)(sa + 0),  a1 = *(const float4*)(sa + 4);
      const float4 a2 = *(const float4*)(sa + 8),  a3 = *(const float4*)(sa + 12);
      *(bf16x8*)&Asb[srow][skh]     = cvt8(a0, a1);
      *(bf16x8*)&Asb[srow][skh + 8] = cvt8(a2, a3);
      const float* sb = Fb + (size_t)(c0 + srow) * D + kk + skh;
      const float4 b0 = *(const float4*)(sb + 0),  b1 = *(const float4*)(sb + 4);
      const float4 b2 = *(const float4*)(sb + 8),  b3 = *(const float4*)(sb + 12);
      *(bf16x8*)&Bsb[srow][skh]     = cvt8(b0, b1);
      *(bf16x8*)&Bsb[srow][skh + 8] = cvt8(b2, b3);
    }
    __syncthreads();
    bf16x8 af[2], bf[8];
    #pragma unroll
    for (int tm = 0; tm < 2; ++tm)
      af[tm] = *(bf16x8*)&Asb[wave * 32 + tm * 16 + l15][quad * 8];
    #pragma unroll
    for (int tn = 0; tn < 8; ++tn)
      bf[tn] = *(bf16x8*)&Bsb[tn * 16 + l15][quad * 8];
    #pragma unroll
    for (int tm = 0; tm < 2; ++tm)
      #pragma unroll
      for (int tn = 0; tn < 8; ++tn)
        acc[tm][tn] = __builtin_amdgcn_mfma_f32_16x16x32_bf16(af[tm], bf[tn], acc[tm][tn], 0, 0, 0);
  }

  // epilogue: exp, zero diag, store, row-degree atomics
  float rs[2][4] = {{0.f, 0.f, 0.f, 0.f}, {0.f, 0.f, 0.f, 0.f}};
  #pragma unroll
  for (int tm = 0; tm < 2; ++tm) {
    const int grb = r0 + wave * 32 + tm * 16 + quad * 4;
    #pragma unroll
    for (int tn = 0; tn < 8; ++tn) {
      const int gc = c0 + tn * 16 + l15;
      #pragma unroll
      for (int r = 0; r < 4; ++r) {
        const int gr = grb + r;
        const float wv = (gr == gc) ? 0.f : __expf(acc[tm][tn][r]);
        Wb[(size_t)gr * K + gc] = wv;
        rs[tm][r] += wv;
      }
    }
  }
  #pragma unroll
  for (int tm = 0; tm < 2; ++tm)
    #pragma unroll
    for (int r = 0; r < 4; ++r) {
      float v = rs[tm][r];
      v += __shfl_xor(v, 1, 64); v += __shfl_xor(v, 2, 64);
      v += __shfl_xor(v, 4, 64); v += __shfl_xor(v, 8, 64);
      if (l15 == 0)
        atomicAdd(&Dg[(size_t)b * K + r0 + wave * 32 + tm * 16 + quad * 4 + r], v);
    }
}

// ===== one Neumann term per launch: w' = a(dinv o (W (dinv o w)) - v (v.w)) =====
__global__ __launch_bounds__(256) void iter_kernel(
    const float* __restrict__ W, const float* __restrict__ Dg,
    const unsigned long long* __restrict__ m0, const unsigned long long* __restrict__ m1,
    const float* __restrict__ u_in, float* __restrict__ u_out,
    float* __restrict__ z, float* __restrict__ out, const int mode)
{
  const int b = blockIdx.y;
  const int r0 = blockIdx.x * 128;
  const float* Wb = W + (size_t)b * (K * K);
  __shared__ __align__(16) float dinv_s[K], sqd_s[K], t0[K], t1[K];
  __shared__ float red[12];
  const int t = threadIdx.x;
  const int wave = t >> 6, lane = t & 63;
  const int a0 = (int)(m0[b] & 0xffffffffu);
  const int a1 = (int)(m1[b] & 0xffffffffu);

  float dsum = 0.f, p0 = 0.f, p1 = 0.f;
  if (mode == 0) {
    for (int k = t; k < K; k += 256) {
      const float d = Dg[(size_t)b * K + k];
      const float sq = sqrtf(d);
      const float di = 1.0f / sqrtf(d + EPSF);
      dinv_s[k] = di; sqd_s[k] = sq; dsum += d;
      t0[k] = (k == a0) ? di : 0.f;
      t1[k] = (k == a1) ? di : 0.f;
    }
  } else {
    const float* ui0 = u_in + (size_t)b * 2 * K;
    const float* ui1 = ui0 + K;
    for (int k = t; k < K; k += 256) {
      const float d = Dg[(size_t)b * K + k];
      const float sq = sqrtf(d);
      const float di = 1.0f / sqrtf(d + EPSF);
      dinv_s[k] = di; sqd_s[k] = sq; dsum += d;
      const float u0v = ui0[k], u1v = ui1[k];
      t0[k] = di * u0v; t1[k] = di * u1v;
      p0 += sq * u0v; p1 += sq * u1v;
    }
  }
  #pragma unroll
  for (int off = 32; off >= 1; off >>= 1) {
    dsum += __shfl_down(dsum, off, 64);
    p0   += __shfl_down(p0,   off, 64);
    p1   += __shfl_down(p1,   off, 64);
  }
  if (lane == 0) { red[wave] = dsum; red[4 + wave] = p0; red[8 + wave] = p1; }
  __syncthreads();
  const float vn = 1.0f / sqrtf(red[0] + red[1] + red[2] + red[3]);
  float s0, s1;
  if (mode == 0) { s0 = vn * sqd_s[a0]; s1 = vn * sqd_s[a1]; }
  else { s0 = vn * (red[4] + red[5] + red[6] + red[7]);
         s1 = vn * (red[8] + red[9] + red[10] + red[11]); }

  float* uo0 = u_out + (size_t)b * 2 * K;
  float* uo1 = uo0 + K;
  float2* zb = (float2*)(z + (size_t)b * K * 2);
  float2* ob = (float2*)(out + (size_t)b * K * 2);
  const float c99 = ALPHA / (1.0f - ALPHA);
  const float cva0 = c99 * vn * sqd_s[a0];
  const float cva1 = c99 * vn * sqd_s[a1];
  const int sub = lane >> 4, cg = lane & 15;

  for (int pass = 0; pass < 8; ++pass) {
    const int r = r0 + wave * 32 + pass * 4 + sub;
    float q0 = 0.f, q1 = 0.f;
    if (mode == 0) {
      if (cg == 0) {
        q0 = Wb[(size_t)r * K + a0] * dinv_s[a0];
        q1 = Wb[(size_t)r * K + a1] * dinv_s[a1];
      }
    } else {
      const float* wrow = Wb + (size_t)r * K;
      #pragma unroll
      for (int q = 0; q < 8; ++q) {
        const int c = q * 64 + cg * 4;
        const float4 wv = *(const float4*)(wrow + c);
        const float4 x0 = *(const float4*)(t0 + c);
        const float4 x1 = *(const float4*)(t1 + c);
        q0 += wv.x*x0.x + wv.y*x0.y + wv.z*x0.z + wv.w*x0.w;
        q1 += wv.x*x1.x + wv.y*x1.y + wv.z*x1.z + wv.w*x1.w;
      }
      q0 += __shfl_xor(q0, 1, 64); q0 += __shfl_xor(q0, 2, 64);
      q0 += __shfl_xor(q0, 4, 64); q0 += __shfl_xor(q0, 8, 64);
      q1 += __shfl_xor(q1, 1, 64); q1 += __shfl_xor(q1, 2, 64);
      q1 += __shfl_xor(q1, 4, 64); q1 += __shfl_xor(q1, 8, 64);
    }
    if (cg == 0) {
      const float di = dinv_s[r];
      const float vr = vn * sqd_s[r];
      const float w0n = ALPHA * (di * q0 - vr * s0);
      const float w1n = ALPHA * (di * q1 - vr * s1);
      if (mode == 0) {
        uo0[r] = w0n; uo1[r] = w1n;
        float2 zv;
        zv.x = ((r == a0) ? 1.f : 0.f) + w0n;
        zv.y = ((r == a1) ? 1.f : 0.f) + w1n;
        zb[r] = zv;
      } else if (mode == 1) {
        uo0[r] = w0n; uo1[r] = w1n;
        float2 zv = zb[r]; zv.x += w0n; zv.y += w1n; zb[r] = zv;
      } else {
        const float2 zv = zb[r];
        float2 o;
        o.x = zv.x + w0n + cva0 * vr;
        o.y = zv.y + w1n + cva1 * vr;
        ob[r] = o;
      }
    }
  }
}

// ==========================================================================
extern "C" void kernel_launch(void* const* d_in, const int* in_sizes, int n_in,
                              void* d_out, int out_size, void* d_ws, size_t ws_size,
                              hipStream_t stream) {
  const float* F = (const float*)d_in[0];   // [B,K,D]
  const float* Q = (const float*)d_in[1];   // [B,D]
  float* out = (float*)d_out;               // [B,K,2]
  const int B = in_sizes[1] / D;            // 128

  float* Wbuf = (float*)d_ws;                            // B*K*K
  float* Dg   = Wbuf + (size_t)B * K * K;                // B*K
  float* uA   = Dg + (size_t)B * K;                      // B*2*K
  float* uB   = uA + (size_t)B * 2 * K;                  // B*2*K
  float* zbuf = uB + (size_t)B * 2 * K;                  // B*K*2
  float* simb = zbuf + (size_t)B * K * 2;                // B*K
  unsigned long long* m0 = (unsigned long long*)(simb + (size_t)B * K);  // B
  unsigned long long* m1 = m0 + B;                                       // B

  hipMemsetAsync(Dg, 0, (size_t)B * K * sizeof(float), stream);
  hipMemsetAsync(m0, 0xFF, 2 * (size_t)B * sizeof(unsigned long long), stream);
  sim1_kernel<<<dim3(8, B), 256, 0, stream>>>(F, Q, simb, m0);
  sim2_kernel<<<dim3(8, B), 256, 0, stream>>>(F, simb, m0, m1);
  gram_mfma_kernel<<<dim3(4, 4, B), 256, 0, stream>>>(F, Wbuf, Dg);
  iter_kernel<<<dim3(4, B), 256, 0, stream>>>(Wbuf, Dg, m0, m1, uB, uA, zbuf, out, 0);
  iter_kernel<<<dim3(4, B), 256, 0, stream>>>(Wbuf, Dg, m0, m1, uA, uB, zbuf, out, 1);
  iter_kernel<<<dim3(4, B), 256, 0, stream>>>(Wbuf, Dg, m0, m1, uB, uA, zbuf, out, 2);
}